// Round 7
// baseline (233.478 us; speedup 1.0000x reference)
//
#include <hip/hip_runtime.h>

// QuantizedTopKSparsity on (8192, 4096) f32.
// Math collapse: gamma = rowmax(|x|) => |x/(gamma+eps)| < 1, so
// x_q = round(x/(gamma+eps)) in {-1,0,1}; abs_q in {0,1}; top-k thresh is 0
// or 1, and either way x_q * mask == x_q.  Output = rintf(x/(gamma+1e-6f)).
//
// R7: attack load-queue DUTY CYCLE. Prior kernels: load burst -> drain
// (row-max dep) -> compute -> store -> next loads; the read queue is empty
// ~half the time per wave. Now each wave owns a ROW PAIR and issues ALL 32
// float4 loads (both rows, 32KB in flight) before any dependency wait, then
// computes+stores both rows with zero further load stalls.
// __launch_bounds__(256,2) -> 256-VGPR budget so ~150 VGPR (128 data) fits
// without the compiler restructuring (R3 lesson: default budget silently
// re-loads). Cached loads (L2/L3 help across generations); NT stores so the
// write-once output stream doesn't evict x from L3.

#define ROWS 8192
#define ROW_D 4096
#define BLOCK 256
#define GRID 1024           // 4096 waves; wave w handles rows w and w+4096
#define EPS_Q 1e-6f

typedef float v4f __attribute__((ext_vector_type(4)));

__device__ __forceinline__ float absmax4(v4f v) {
    return fmaxf(fmaxf(fabsf(v.x), fabsf(v.y)), fmaxf(fabsf(v.z), fabsf(v.w)));
}

__global__ __launch_bounds__(BLOCK, 2) void qtern_kernel(const float* __restrict__ x,
                                                         float* __restrict__ out) {
    const int wave = threadIdx.x >> 6;
    const int lane = threadIdx.x & 63;
    const int wid = blockIdx.x * (BLOCK / 64) + wave;  // 0..4095

    const long long rowA = wid;
    const long long rowB = wid + 4096;
    const v4f* __restrict__ xA = reinterpret_cast<const v4f*>(x + rowA * (long long)ROW_D);
    const v4f* __restrict__ xB = reinterpret_cast<const v4f*>(x + rowB * (long long)ROW_D);
    v4f* __restrict__ oA = reinterpret_cast<v4f*>(out + rowA * (long long)ROW_D);
    v4f* __restrict__ oB = reinterpret_cast<v4f*>(out + rowB * (long long)ROW_D);

    // Issue ALL 32 loads (2 rows x 16 v4) back-to-back: 32KB in flight/wave.
    v4f a[16], b[16];
#pragma unroll
    for (int i = 0; i < 16; ++i) a[i] = xA[lane + 64 * i];
#pragma unroll
    for (int i = 0; i < 16; ++i) b[i] = xB[lane + 64 * i];

    // Row A: reduce, quantize, store (NT: write-once stream, keep L3 for x).
    float mA = 0.0f;
#pragma unroll
    for (int i = 0; i < 16; ++i) mA = fmaxf(mA, absmax4(a[i]));
#pragma unroll
    for (int off = 32; off; off >>= 1) mA = fmaxf(mA, __shfl_xor(mA, off));
    const float dA = mA + EPS_Q;
#pragma unroll
    for (int i = 0; i < 16; ++i) {
        v4f o;
        // rintf = round-half-even (matches np.round); true IEEE '/' so
        // boundary cases match the numpy reference exactly.
        o.x = rintf(a[i].x / dA);
        o.y = rintf(a[i].y / dA);
        o.z = rintf(a[i].z / dA);
        o.w = rintf(a[i].w / dA);
        __builtin_nontemporal_store(o, &oA[lane + 64 * i]);
    }

    // Row B: loads were in flight the whole time; no fresh load stall.
    float mB = 0.0f;
#pragma unroll
    for (int i = 0; i < 16; ++i) mB = fmaxf(mB, absmax4(b[i]));
#pragma unroll
    for (int off = 32; off; off >>= 1) mB = fmaxf(mB, __shfl_xor(mB, off));
    const float dB = mB + EPS_Q;
#pragma unroll
    for (int i = 0; i < 16; ++i) {
        v4f o;
        o.x = rintf(b[i].x / dB);
        o.y = rintf(b[i].y / dB);
        o.z = rintf(b[i].z / dB);
        o.w = rintf(b[i].w / dB);
        __builtin_nontemporal_store(o, &oB[lane + 64 * i]);
    }
}

extern "C" void kernel_launch(void* const* d_in, const int* in_sizes, int n_in,
                              void* d_out, int out_size, void* d_ws, size_t ws_size,
                              hipStream_t stream) {
    const float* x = (const float*)d_in[0];
    float* out = (float*)d_out;
    qtern_kernel<<<GRID, BLOCK, 0, stream>>>(x, out);
}